// Round 5
// baseline (388.102 us; speedup 1.0000x reference)
//
#include <hip/hip_runtime.h>

// dims
#define L_   384
#define D_   512
#define C_   256
#define H_   4
#define RR_  256
#define M1_  98304   // R*L
#define LL2_ 147456  // L*L
#define NPAIR_BLOCKS 18480  // 73920 pairs / 4 waves per block
#define TILE_ELEMS (128 * 64)

typedef __bf16 bf16x8 __attribute__((ext_vector_type(8)));
typedef float f32x4 __attribute__((ext_vector_type(4)));

__device__ __forceinline__ unsigned short f2bf_bits(float f) {
  union { float f; unsigned u; } v; v.f = f;
  return (unsigned short)((v.u + 0x7fffu + ((v.u >> 16) & 1u)) >> 16);
}
__device__ __forceinline__ __bf16 f2bf(float f) {
  union { unsigned short s; __bf16 b; } o; o.s = f2bf_bits(f);
  return o.b;
}

__device__ __forceinline__ float wave_sum(float v) {
#pragma unroll
  for (int o = 32; o > 0; o >>= 1) v += __shfl_xor(v, o);
  return v;
}
__device__ __forceinline__ float wave_max(float v) {
#pragma unroll
  for (int o = 32; o > 0; o >>= 1) v = fmaxf(v, __shfl_xor(v, o));
  return v;
}

// ---------------- K1: LayerNorm(x) -> msa (bf16), wave-per-row ----------------
__global__ __launch_bounds__(256) void ln_msa_kernel(
    const float* __restrict__ x, const float* __restrict__ g,
    const float* __restrict__ b, __bf16* __restrict__ msa) {
  int row = blockIdx.x * 4 + (threadIdx.x >> 6);
  int lane = threadIdx.x & 63;
  const float4* xr = (const float4*)(x + (size_t)row * D_ + lane * 8);
  float4 v0 = xr[0], v1 = xr[1];
  float s1 = v0.x + v0.y + v0.z + v0.w + v1.x + v1.y + v1.z + v1.w;
  float s2 = v0.x * v0.x + v0.y * v0.y + v0.z * v0.z + v0.w * v0.w +
             v1.x * v1.x + v1.y * v1.y + v1.z * v1.z + v1.w * v1.w;
#pragma unroll
  for (int o = 32; o > 0; o >>= 1) {
    s1 += __shfl_xor(s1, o);
    s2 += __shfl_xor(s2, o);
  }
  float mu = s1 * (1.0f / D_);
  float var = s2 * (1.0f / D_) - mu * mu;
  float rs = rsqrtf(var + 1e-5f);
  const float4* gp = (const float4*)(g + lane * 8);
  const float4* bp = (const float4*)(b + lane * 8);
  float4 g0 = gp[0], g1 = gp[1], b0 = bp[0], b1 = bp[1];
  float y[8];
  y[0] = (v0.x - mu) * rs * g0.x + b0.x;
  y[1] = (v0.y - mu) * rs * g0.y + b0.y;
  y[2] = (v0.z - mu) * rs * g0.z + b0.z;
  y[3] = (v0.w - mu) * rs * g0.w + b0.w;
  y[4] = (v1.x - mu) * rs * g1.x + b1.x;
  y[5] = (v1.y - mu) * rs * g1.y + b1.y;
  y[6] = (v1.z - mu) * rs * g1.z + b1.z;
  y[7] = (v1.w - mu) * rs * g1.w + b1.w;
  uint4 pk;
  pk.x = ((unsigned)f2bf_bits(y[1]) << 16) | f2bf_bits(y[0]);
  pk.y = ((unsigned)f2bf_bits(y[3]) << 16) | f2bf_bits(y[2]);
  pk.z = ((unsigned)f2bf_bits(y[5]) << 16) | f2bf_bits(y[4]);
  pk.w = ((unsigned)f2bf_bits(y[7]) << 16) | f2bf_bits(y[6]);
  *(uint4*)(msa + (size_t)row * D_ + lane * 8) = pk;
}

// ------ K3: pair symmetrize + LN + per-head logits (+mask) ------
__global__ __launch_bounds__(256) void pair_logits_kernel(
    const float* __restrict__ pf, const int* __restrict__ mask,
    const float* __restrict__ g, const float* __restrict__ b,
    const float* __restrict__ Wp, float* __restrict__ logits) {
  unsigned wid = blockIdx.x * 4 + (threadIdx.x >> 6);  // 0..73919
  int lane = threadIdx.x & 63;
  unsigned a = wid / 385u;
  unsigned c = wid - a * 385u;
  int i, j;
  if (c < 384u - a) { i = a; j = a + c; }
  else { i = 383 - a; j = i + (c - (384 - a)); }

  int c0 = lane * 4;
  float4 p1 = *(const float4*)(pf + ((size_t)i * L_ + j) * C_ + c0);
  float4 p2 = *(const float4*)(pf + ((size_t)j * L_ + i) * C_ + c0);
  float4 v;
  v.x = 0.5f * (p1.x + p2.x); v.y = 0.5f * (p1.y + p2.y);
  v.z = 0.5f * (p1.z + p2.z); v.w = 0.5f * (p1.w + p2.w);
  float s1 = v.x + v.y + v.z + v.w;
  float s2 = v.x * v.x + v.y * v.y + v.z * v.z + v.w * v.w;
#pragma unroll
  for (int o = 32; o > 0; o >>= 1) {
    s1 += __shfl_xor(s1, o);
    s2 += __shfl_xor(s2, o);
  }
  float mu = s1 * (1.0f / C_);
  float var = s2 * (1.0f / C_) - mu * mu;
  float rs = rsqrtf(var + 1e-5f);
  float4 gv = *(const float4*)(g + c0);
  float4 bv = *(const float4*)(b + c0);
  float y0 = (v.x - mu) * rs * gv.x + bv.x;
  float y1 = (v.y - mu) * rs * gv.y + bv.y;
  float y2 = (v.z - mu) * rs * gv.z + bv.z;
  float y3 = (v.w - mu) * rs * gv.w + bv.w;
  const float4* wp = (const float4*)Wp;  // [256][4]
  float4 w0 = wp[c0], w1 = wp[c0 + 1], w2 = wp[c0 + 2], w3 = wp[c0 + 3];
  float4 t;
  t.x = y0 * w0.x + y1 * w1.x + y2 * w2.x + y3 * w3.x;
  t.y = y0 * w0.y + y1 * w1.y + y2 * w2.y + y3 * w3.y;
  t.z = y0 * w0.z + y1 * w1.z + y2 * w2.z + y3 * w3.z;
  t.w = y0 * w0.w + y1 * w1.w + y2 * w2.w + y3 * w3.w;
#pragma unroll
  for (int o = 32; o > 0; o >>= 1) {
    t.x += __shfl_xor(t.x, o);
    t.y += __shfl_xor(t.y, o);
    t.z += __shfl_xor(t.z, o);
    t.w += __shfl_xor(t.w, o);
  }
  if (lane < 8) {
    int h = lane & 3;
    int ii = (lane < 4) ? i : j;
    int jj = (lane < 4) ? j : i;
    bool ok = (mask[i] != 0) && (mask[j] != 0);
    const float NEG = -3.402823466e38f;
    const float SCALE = (float)(0.08838834764831845 / 19.595917942265423);
    float th = (h == 0) ? t.x : (h == 1) ? t.y : (h == 2) ? t.z : t.w;
    logits[(size_t)h * LL2_ + (size_t)ii * L_ + jj] = ok ? SCALE * th : NEG;
  }
}

// ---------------- K4: row softmax -> attn (bf16) ----------------
__global__ __launch_bounds__(256) void softmax_kernel(
    const float* __restrict__ logits, __bf16* __restrict__ attn) {
  int wave = threadIdx.x >> 6, lane = threadIdx.x & 63;
  int row = blockIdx.x * 4 + wave;  // 0..1535 (= h*384 + i)
  const float* lr = logits + (size_t)row * L_;
  float v[6];
#pragma unroll
  for (int t = 0; t < 6; ++t) v[t] = lr[lane + t * 64];
  float mx = v[0];
#pragma unroll
  for (int t = 1; t < 6; ++t) mx = fmaxf(mx, v[t]);
  mx = wave_max(mx);
  float s = 0.f;
#pragma unroll
  for (int t = 0; t < 6; ++t) { v[t] = __expf(v[t] - mx); s += v[t]; }
  s = wave_sum(s);
  float inv = 1.0f / s;
  __bf16* ar = attn + (size_t)row * L_;
#pragma unroll
  for (int t = 0; t < 6; ++t) ar[lane + t * 64] = f2bf(v[t] * inv);
}

// ------------- K0: transpose W_v, W_out -> bf16 -----------------
__global__ __launch_bounds__(256) void wtrans_kernel(
    const float* __restrict__ Wv, const float* __restrict__ Wo,
    __bf16* __restrict__ WvT, __bf16* __restrict__ WoT) {
  int id = blockIdx.x * 256 + threadIdx.x;  // 0..524287
  int m = id >> 18;
  int e = (id >> 9) & 511, d = id & 511;
  const float* W = m ? Wo : Wv;
  __bf16* T = m ? WoT : WvT;
  T[(size_t)e * 512 + d] = f2bf(W[(size_t)d * 512 + e]);
}

// ---------------- shared GEMM machinery (bt form) ----------------
// LDS tile image: [128 rows][64 k] bf16, rows 128B, XOR-swizzled by ((row&7)<<4).
// Staged via global_load_lds: LINEAR LDS dest + INVERSE-swizzled global source.
// 2-deep pipeline with COUNTED vmcnt (T4): per wave, wait only the current
// tile's 8 loads (vmcnt(8) leaves next tile's 8 in flight), then raw s_barrier.
// Never drains to vmcnt(0) until the last tile.
__device__ __forceinline__ void gload16(const void* g, void* l) {
  __builtin_amdgcn_global_load_lds(
      (const __attribute__((address_space(1))) void*)g,
      (__attribute__((address_space(3))) void*)l, 16, 0, 0);
}

__device__ __forceinline__ void stage_tile_async(__bf16* s, const __bf16* g, size_t ld) {
  int tid = threadIdx.x;
#pragma unroll
  for (int it = 0; it < 4; ++it) {
    int cid = it * 256 + tid;      // 0..1023 chunks of 16B
    int row = cid >> 3, chk = cid & 7;
    int src_off = (chk * 16) ^ ((row & 7) << 4);   // byte offset within the row
    gload16(g + (size_t)row * ld + (src_off >> 1), (char*)s + cid * 16);
  }
}

__device__ __forceinline__ bf16x8 frag_ld(const __bf16* s, int row, int k) {
  int sb = row * 128 + ((k * 2) ^ ((row & 7) << 4));
  return *(const bf16x8*)((const char*)s + sb);
}

// As, Bs: 2 * TILE_ELEMS each (double-buffered)
__device__ __forceinline__ void gemm_mainloop(
    const __bf16* __restrict__ Arow, size_t ldA,
    const __bf16* __restrict__ Brow, size_t ldB,
    int K, __bf16* As, __bf16* Bs, f32x4 acc[4][4]) {
  int lane = threadIdx.x & 63, wave = threadIdx.x >> 6;
  int wm = (wave >> 1) * 64, wn = (wave & 1) * 64;
  int fr = lane & 15, fk = (lane >> 4) * 8;
  int nt = K >> 6;
  // prologue: stage tiles 0 and 1 (8 gload_lds per thread per tile-pair)
  stage_tile_async(As, Arow, ldA);
  stage_tile_async(Bs, Brow, ldB);
  stage_tile_async(As + TILE_ELEMS, Arow + 64, ldA);
  stage_tile_async(Bs + TILE_ELEMS, Brow + 64, ldB);
  int cur = 0;
  for (int t = 0; t < nt; ++t) {
    // wait for buf[cur]'s own 8 loads; keep the next tile's 8 in flight
    if (t + 1 < nt) asm volatile("s_waitcnt vmcnt(8)" ::: "memory");
    else            asm volatile("s_waitcnt vmcnt(0)" ::: "memory");
    __builtin_amdgcn_s_barrier();   // + all other waves' writes to buf[cur] done
    __builtin_amdgcn_sched_barrier(0);
    const __bf16* Ab = As + cur * TILE_ELEMS;
    const __bf16* Bb = Bs + cur * TILE_ELEMS;
#pragma unroll
    for (int kk = 0; kk < 2; ++kk) {
      bf16x8 af[4], bfv[4];
#pragma unroll
      for (int mi = 0; mi < 4; ++mi) af[mi] = frag_ld(Ab, wm + mi * 16 + fr, kk * 32 + fk);
#pragma unroll
      for (int ni = 0; ni < 4; ++ni) bfv[ni] = frag_ld(Bb, wn + ni * 16 + fr, kk * 32 + fk);
#pragma unroll
      for (int mi = 0; mi < 4; ++mi)
#pragma unroll
        for (int ni = 0; ni < 4; ++ni)
          acc[mi][ni] = __builtin_amdgcn_mfma_f32_16x16x32_bf16(af[mi], bfv[ni], acc[mi][ni], 0, 0, 0);
    }
    __builtin_amdgcn_sched_barrier(0);
    __builtin_amdgcn_s_barrier();   // all waves done reading buf[cur]
    if (t + 2 < nt) {               // re-stage into the buffer just consumed
      stage_tile_async(As + cur * TILE_ELEMS, Arow + (size_t)(t + 2) * 64, ldA);
      stage_tile_async(Bs + cur * TILE_ELEMS, Brow + (size_t)(t + 2) * 64, ldB);
    }
    cur ^= 1;
  }
}

// XCD-chunked swizzle: 3072 blocks, 8 XCDs -> 384-block contiguous chunk per XCD.
__device__ __forceinline__ unsigned xcd_swz_3072(unsigned bid) {
  return (bid & 7u) * 384u + (bid >> 3);
}

// ---- K2: VT[e][m] = sum_d WvT[e][d] * msa[m][d]  (= V^T) ----
__global__ __launch_bounds__(256) void gemm_vt_kernel(
    const __bf16* __restrict__ WvT, const __bf16* __restrict__ msa,
    __bf16* __restrict__ VT) {
  __shared__ __bf16 As[2 * TILE_ELEMS], Bs[2 * TILE_ELEMS];
  unsigned swz = xcd_swz_3072(blockIdx.x + 4 * blockIdx.y);
  int m0 = (swz & 3) * 128;        // WvT tile (share-group of 4 stays contiguous)
  int n0 = (swz >> 2) * 128;       // msa panel
  f32x4 acc[4][4] = {};
  gemm_mainloop(WvT + (size_t)m0 * D_, D_, msa + (size_t)n0 * D_, D_, D_, As, Bs, acc);
  int lane = threadIdx.x & 63, wave = threadIdx.x >> 6;
  int wm = (wave >> 1) * 64, wn = (wave & 1) * 64;
  int cr = (lane >> 4) * 4, cc = lane & 15;
#pragma unroll
  for (int mi = 0; mi < 4; ++mi)
#pragma unroll
    for (int ni = 0; ni < 4; ++ni)
#pragma unroll
      for (int rr = 0; rr < 4; ++rr) {
        int row = m0 + wm + mi * 16 + cr + rr;
        int col = n0 + wn + ni * 16 + cc;
        VT[(size_t)row * M1_ + col] = f2bf(acc[mi][ni][rr]);
      }
}

// ---- K5: out2[(r,i)][h*128+d] = sum_j attn[h][i][j] * VT[h*128+d][r*384+j] ----
__global__ __launch_bounds__(256) void attnv_kernel(
    const __bf16* __restrict__ attn, const __bf16* __restrict__ VT,
    __bf16* __restrict__ out2) {
  __shared__ __bf16 As[2 * TILE_ELEMS], Bs[2 * TILE_ELEMS];
  unsigned swz = xcd_swz_3072(blockIdx.x + 3 * blockIdx.y);
  int it = swz % 3u;               // i-tile (share-group of 3; 384 % 3 == 0)
  int rh = swz / 3u;               // 0..1023
  int h = rh & 3, r = rh >> 2;
  const __bf16* A = attn + (size_t)h * LL2_ + (size_t)it * 128 * L_;
  const __bf16* Bt = VT + (size_t)(h * 128) * M1_ + (size_t)r * L_;
  f32x4 acc[4][4] = {};
  gemm_mainloop(A, L_, Bt, M1_, L_, As, Bs, acc);
  int lane = threadIdx.x & 63, wave = threadIdx.x >> 6;
  int wm = (wave >> 1) * 64, wn = (wave & 1) * 64;
  int cr = (lane >> 4) * 4, cc = lane & 15;
#pragma unroll
  for (int mi = 0; mi < 4; ++mi)
#pragma unroll
    for (int ni = 0; ni < 4; ++ni)
#pragma unroll
      for (int rr = 0; rr < 4; ++rr) {
        int row_i = it * 128 + wm + mi * 16 + cr + rr;
        int col = h * 128 + wn + ni * 16 + cc;
        out2[((size_t)r * L_ + row_i) * D_ + col] = f2bf(acc[mi][ni][rr]);
      }
}

// ---- K6: out[m][f] = x[m][f] + sum_e out2[m][e] * WoT[f][e] ----
__global__ __launch_bounds__(256) void gemm_out_kernel(
    const __bf16* __restrict__ out2, const __bf16* __restrict__ WoT,
    const float* __restrict__ x, float* __restrict__ out) {
  __shared__ __bf16 As[2 * TILE_ELEMS], Bs[2 * TILE_ELEMS];
  unsigned swz = xcd_swz_3072(blockIdx.x + 4 * blockIdx.y);
  int n0 = (swz & 3) * 128;        // WoT tile
  int m0 = (swz >> 2) * 128;       // out2 panel
  f32x4 acc[4][4] = {};
  gemm_mainloop(out2 + (size_t)m0 * D_, D_, WoT + (size_t)n0 * D_, D_, D_, As, Bs, acc);
  int lane = threadIdx.x & 63, wave = threadIdx.x >> 6;
  int wm = (wave >> 1) * 64, wn = (wave & 1) * 64;
  int cr = (lane >> 4) * 4, cc = lane & 15;
#pragma unroll
  for (int mi = 0; mi < 4; ++mi)
#pragma unroll
    for (int ni = 0; ni < 4; ++ni)
#pragma unroll
      for (int rr = 0; rr < 4; ++rr) {
        int row = m0 + wm + mi * 16 + cr + rr;
        int col = n0 + wn + ni * 16 + cc;
        size_t idx = (size_t)row * D_ + col;
        out[idx] = x[idx] + acc[mi][ni][rr];
      }
}

extern "C" void kernel_launch(void* const* d_in, const int* in_sizes, int n_in,
                              void* d_out, int out_size, void* d_ws, size_t ws_size,
                              hipStream_t stream) {
  const float* x      = (const float*)d_in[0];
  const float* pair   = (const float*)d_in[1];
  const int*   mask   = (const int*)d_in[2];
  const float* g_msa  = (const float*)d_in[3];
  const float* b_msa  = (const float*)d_in[4];
  const float* g_pair = (const float*)d_in[5];
  const float* b_pair = (const float*)d_in[6];
  const float* Wp     = (const float*)d_in[7];
  const float* Wv     = (const float*)d_in[8];
  const float* Wo     = (const float*)d_in[9];
  float* out = (float*)d_out;

  char* p = (char*)d_ws;
  auto alloc = [&](size_t bytes) {
    char* r = p;
    p += (bytes + 255) & ~(size_t)255;
    return r;
  };
  __bf16* msa    = (__bf16*)alloc((size_t)M1_ * D_ * 2);  // 100.7 MB (aliased as out2 later)
  __bf16* VT     = (__bf16*)alloc((size_t)D_ * M1_ * 2);  // 100.7 MB
  float*  logits = (float*)alloc((size_t)H_ * LL2_ * 4);  // 2.36 MB
  __bf16* attn   = (__bf16*)alloc((size_t)H_ * LL2_ * 2); // 1.18 MB
  __bf16* WvT    = (__bf16*)alloc((size_t)512 * 512 * 2);
  __bf16* WoT    = (__bf16*)alloc((size_t)512 * 512 * 2);
  __bf16* out2   = msa;  // msa dead after gemm_vt_kernel

  wtrans_kernel<<<2048, 256, 0, stream>>>(Wv, Wo, WvT, WoT);
  ln_msa_kernel<<<M1_ / 4, 256, 0, stream>>>(x, g_msa, b_msa, msa);
  gemm_vt_kernel<<<dim3(4, M1_ / 128), 256, 0, stream>>>(WvT, msa, VT);
  pair_logits_kernel<<<NPAIR_BLOCKS, 256, 0, stream>>>(pair, mask, g_pair, b_pair, Wp, logits);
  softmax_kernel<<<(H_ * L_) / 4, 256, 0, stream>>>(logits, attn);
  attnv_kernel<<<dim3(3, RR_ * H_), 256, 0, stream>>>(attn, VT, out2);
  gemm_out_kernel<<<dim3(4, M1_ / 128), 256, 0, stream>>>(out2, WoT, x, out);
}

// Round 6
// 375.655 us; speedup vs baseline: 1.0331x; 1.0331x over previous
//
#include <hip/hip_runtime.h>

// dims
#define L_   384
#define D_   512
#define C_   256
#define H_   4
#define RR_  256
#define M1_  98304   // R*L
#define LL2_ 147456  // L*L
#define NPAIR_BLOCKS 18480  // 73920 pairs / 4 waves per block
#define TILE_ELEMS (128 * 64)
#define TILE256_ELEMS (256 * 64)

typedef __bf16 bf16x8 __attribute__((ext_vector_type(8)));
typedef float f32x4 __attribute__((ext_vector_type(4)));

__device__ __forceinline__ unsigned short f2bf_bits(float f) {
  union { float f; unsigned u; } v; v.f = f;
  return (unsigned short)((v.u + 0x7fffu + ((v.u >> 16) & 1u)) >> 16);
}
__device__ __forceinline__ __bf16 f2bf(float f) {
  union { unsigned short s; __bf16 b; } o; o.s = f2bf_bits(f);
  return o.b;
}

__device__ __forceinline__ float wave_sum(float v) {
#pragma unroll
  for (int o = 32; o > 0; o >>= 1) v += __shfl_xor(v, o);
  return v;
}
__device__ __forceinline__ float wave_max(float v) {
#pragma unroll
  for (int o = 32; o > 0; o >>= 1) v = fmaxf(v, __shfl_xor(v, o));
  return v;
}

// ---------------- K1: LayerNorm(x) -> msa (bf16), wave-per-row ----------------
__global__ __launch_bounds__(256) void ln_msa_kernel(
    const float* __restrict__ x, const float* __restrict__ g,
    const float* __restrict__ b, __bf16* __restrict__ msa) {
  int row = blockIdx.x * 4 + (threadIdx.x >> 6);
  int lane = threadIdx.x & 63;
  const float4* xr = (const float4*)(x + (size_t)row * D_ + lane * 8);
  float4 v0 = xr[0], v1 = xr[1];
  float s1 = v0.x + v0.y + v0.z + v0.w + v1.x + v1.y + v1.z + v1.w;
  float s2 = v0.x * v0.x + v0.y * v0.y + v0.z * v0.z + v0.w * v0.w +
             v1.x * v1.x + v1.y * v1.y + v1.z * v1.z + v1.w * v1.w;
#pragma unroll
  for (int o = 32; o > 0; o >>= 1) {
    s1 += __shfl_xor(s1, o);
    s2 += __shfl_xor(s2, o);
  }
  float mu = s1 * (1.0f / D_);
  float var = s2 * (1.0f / D_) - mu * mu;
  float rs = rsqrtf(var + 1e-5f);
  const float4* gp = (const float4*)(g + lane * 8);
  const float4* bp = (const float4*)(b + lane * 8);
  float4 g0 = gp[0], g1 = gp[1], b0 = bp[0], b1 = bp[1];
  float y[8];
  y[0] = (v0.x - mu) * rs * g0.x + b0.x;
  y[1] = (v0.y - mu) * rs * g0.y + b0.y;
  y[2] = (v0.z - mu) * rs * g0.z + b0.z;
  y[3] = (v0.w - mu) * rs * g0.w + b0.w;
  y[4] = (v1.x - mu) * rs * g1.x + b1.x;
  y[5] = (v1.y - mu) * rs * g1.y + b1.y;
  y[6] = (v1.z - mu) * rs * g1.z + b1.z;
  y[7] = (v1.w - mu) * rs * g1.w + b1.w;
  uint4 pk;
  pk.x = ((unsigned)f2bf_bits(y[1]) << 16) | f2bf_bits(y[0]);
  pk.y = ((unsigned)f2bf_bits(y[3]) << 16) | f2bf_bits(y[2]);
  pk.z = ((unsigned)f2bf_bits(y[5]) << 16) | f2bf_bits(y[4]);
  pk.w = ((unsigned)f2bf_bits(y[7]) << 16) | f2bf_bits(y[6]);
  *(uint4*)(msa + (size_t)row * D_ + lane * 8) = pk;
}

// ------ K3: pair symmetrize + LN + per-head logits (+mask) ------
__global__ __launch_bounds__(256) void pair_logits_kernel(
    const float* __restrict__ pf, const int* __restrict__ mask,
    const float* __restrict__ g, const float* __restrict__ b,
    const float* __restrict__ Wp, float* __restrict__ logits) {
  unsigned wid = blockIdx.x * 4 + (threadIdx.x >> 6);  // 0..73919
  int lane = threadIdx.x & 63;
  unsigned a = wid / 385u;
  unsigned c = wid - a * 385u;
  int i, j;
  if (c < 384u - a) { i = a; j = a + c; }
  else { i = 383 - a; j = i + (c - (384 - a)); }

  int c0 = lane * 4;
  float4 p1 = *(const float4*)(pf + ((size_t)i * L_ + j) * C_ + c0);
  float4 p2 = *(const float4*)(pf + ((size_t)j * L_ + i) * C_ + c0);
  float4 v;
  v.x = 0.5f * (p1.x + p2.x); v.y = 0.5f * (p1.y + p2.y);
  v.z = 0.5f * (p1.z + p2.z); v.w = 0.5f * (p1.w + p2.w);
  float s1 = v.x + v.y + v.z + v.w;
  float s2 = v.x * v.x + v.y * v.y + v.z * v.z + v.w * v.w;
#pragma unroll
  for (int o = 32; o > 0; o >>= 1) {
    s1 += __shfl_xor(s1, o);
    s2 += __shfl_xor(s2, o);
  }
  float mu = s1 * (1.0f / C_);
  float var = s2 * (1.0f / C_) - mu * mu;
  float rs = rsqrtf(var + 1e-5f);
  float4 gv = *(const float4*)(g + c0);
  float4 bv = *(const float4*)(b + c0);
  float y0 = (v.x - mu) * rs * gv.x + bv.x;
  float y1 = (v.y - mu) * rs * gv.y + bv.y;
  float y2 = (v.z - mu) * rs * gv.z + bv.z;
  float y3 = (v.w - mu) * rs * gv.w + bv.w;
  const float4* wp = (const float4*)Wp;  // [256][4]
  float4 w0 = wp[c0], w1 = wp[c0 + 1], w2 = wp[c0 + 2], w3 = wp[c0 + 3];
  float4 t;
  t.x = y0 * w0.x + y1 * w1.x + y2 * w2.x + y3 * w3.x;
  t.y = y0 * w0.y + y1 * w1.y + y2 * w2.y + y3 * w3.y;
  t.z = y0 * w0.z + y1 * w1.z + y2 * w2.z + y3 * w3.z;
  t.w = y0 * w0.w + y1 * w1.w + y2 * w2.w + y3 * w3.w;
#pragma unroll
  for (int o = 32; o > 0; o >>= 1) {
    t.x += __shfl_xor(t.x, o);
    t.y += __shfl_xor(t.y, o);
    t.z += __shfl_xor(t.z, o);
    t.w += __shfl_xor(t.w, o);
  }
  if (lane < 8) {
    int h = lane & 3;
    int ii = (lane < 4) ? i : j;
    int jj = (lane < 4) ? j : i;
    bool ok = (mask[i] != 0) && (mask[j] != 0);
    const float NEG = -3.402823466e38f;
    const float SCALE = (float)(0.08838834764831845 / 19.595917942265423);
    float th = (h == 0) ? t.x : (h == 1) ? t.y : (h == 2) ? t.z : t.w;
    logits[(size_t)h * LL2_ + (size_t)ii * L_ + jj] = ok ? SCALE * th : NEG;
  }
}

// ---------------- K4: row softmax -> attn (bf16) ----------------
__global__ __launch_bounds__(256) void softmax_kernel(
    const float* __restrict__ logits, __bf16* __restrict__ attn) {
  int wave = threadIdx.x >> 6, lane = threadIdx.x & 63;
  int row = blockIdx.x * 4 + wave;  // 0..1535 (= h*384 + i)
  const float* lr = logits + (size_t)row * L_;
  float v[6];
#pragma unroll
  for (int t = 0; t < 6; ++t) v[t] = lr[lane + t * 64];
  float mx = v[0];
#pragma unroll
  for (int t = 1; t < 6; ++t) mx = fmaxf(mx, v[t]);
  mx = wave_max(mx);
  float s = 0.f;
#pragma unroll
  for (int t = 0; t < 6; ++t) { v[t] = __expf(v[t] - mx); s += v[t]; }
  s = wave_sum(s);
  float inv = 1.0f / s;
  __bf16* ar = attn + (size_t)row * L_;
#pragma unroll
  for (int t = 0; t < 6; ++t) ar[lane + t * 64] = f2bf(v[t] * inv);
}

// ------------- K0: transpose W_v, W_out -> bf16 -----------------
__global__ __launch_bounds__(256) void wtrans_kernel(
    const float* __restrict__ Wv, const float* __restrict__ Wo,
    __bf16* __restrict__ WvT, __bf16* __restrict__ WoT) {
  int id = blockIdx.x * 256 + threadIdx.x;  // 0..524287
  int m = id >> 18;
  int e = (id >> 9) & 511, d = id & 511;
  const float* W = m ? Wo : Wv;
  __bf16* T = m ? WoT : WvT;
  T[(size_t)e * 512 + d] = f2bf(W[(size_t)d * 512 + e]);
}

// ---------------- shared GEMM machinery (bt form) ----------------
// LDS tile image: [rows][64 k] bf16, rows 128B, XOR-swizzled by ((row&7)<<4).
// Staged via global_load_lds: LINEAR LDS dest + INVERSE-swizzled global source.
__device__ __forceinline__ void gload16(const void* g, void* l) {
  __builtin_amdgcn_global_load_lds(
      (const __attribute__((address_space(1))) void*)g,
      (__attribute__((address_space(3))) void*)l, 16, 0, 0);
}

// 128-row tile, 256 threads: 4 loads/thread
__device__ __forceinline__ void stage_tile_async(__bf16* s, const __bf16* g, size_t ld) {
  int tid = threadIdx.x;
#pragma unroll
  for (int it = 0; it < 4; ++it) {
    int cid = it * 256 + tid;      // 0..1023 chunks of 16B
    int row = cid >> 3, chk = cid & 7;
    int src_off = (chk * 16) ^ ((row & 7) << 4);   // byte offset within the row
    gload16(g + (size_t)row * ld + (src_off >> 1), (char*)s + cid * 16);
  }
}

// 256-row tile, 512 threads: 4 loads/thread
__device__ __forceinline__ void stage_tile256(__bf16* s, const __bf16* g, size_t ld) {
  int tid = threadIdx.x;
#pragma unroll
  for (int it = 0; it < 4; ++it) {
    int cid = it * 512 + tid;      // 0..2047 chunks of 16B
    int row = cid >> 3, chk = cid & 7;
    int src_off = (chk * 16) ^ ((row & 7) << 4);
    gload16(g + (size_t)row * ld + (src_off >> 1), (char*)s + cid * 16);
  }
}

__device__ __forceinline__ bf16x8 frag_ld(const __bf16* s, int row, int k) {
  int sb = row * 128 + ((k * 2) ^ ((row & 7) << 4));
  return *(const bf16x8*)((const char*)s + sb);
}

// ---- 128x128-tile mainloop (256 thr, 4 waves) — used by attnv ----
__device__ __forceinline__ void gemm_mainloop(
    const __bf16* __restrict__ Arow, size_t ldA,
    const __bf16* __restrict__ Brow, size_t ldB,
    int K, __bf16* As, __bf16* Bs, f32x4 acc[4][4]) {
  int lane = threadIdx.x & 63, wave = threadIdx.x >> 6;
  int wm = (wave >> 1) * 64, wn = (wave & 1) * 64;
  int fr = lane & 15, fk = (lane >> 4) * 8;
  int nt = K >> 6;
  stage_tile_async(As, Arow, ldA);
  stage_tile_async(Bs, Brow, ldB);
  stage_tile_async(As + TILE_ELEMS, Arow + 64, ldA);
  stage_tile_async(Bs + TILE_ELEMS, Brow + 64, ldB);
  int cur = 0;
  for (int t = 0; t < nt; ++t) {
    if (t + 1 < nt) asm volatile("s_waitcnt vmcnt(8)" ::: "memory");
    else            asm volatile("s_waitcnt vmcnt(0)" ::: "memory");
    __builtin_amdgcn_s_barrier();
    __builtin_amdgcn_sched_barrier(0);
    const __bf16* Ab = As + cur * TILE_ELEMS;
    const __bf16* Bb = Bs + cur * TILE_ELEMS;
#pragma unroll
    for (int kk = 0; kk < 2; ++kk) {
      bf16x8 af[4], bfv[4];
#pragma unroll
      for (int mi = 0; mi < 4; ++mi) af[mi] = frag_ld(Ab, wm + mi * 16 + fr, kk * 32 + fk);
#pragma unroll
      for (int ni = 0; ni < 4; ++ni) bfv[ni] = frag_ld(Bb, wn + ni * 16 + fr, kk * 32 + fk);
#pragma unroll
      for (int mi = 0; mi < 4; ++mi)
#pragma unroll
        for (int ni = 0; ni < 4; ++ni)
          acc[mi][ni] = __builtin_amdgcn_mfma_f32_16x16x32_bf16(af[mi], bfv[ni], acc[mi][ni], 0, 0, 0);
    }
    __builtin_amdgcn_sched_barrier(0);
    __builtin_amdgcn_s_barrier();
    if (t + 2 < nt) {
      stage_tile_async(As + cur * TILE_ELEMS, Arow + (size_t)(t + 2) * 64, ldA);
      stage_tile_async(Bs + cur * TILE_ELEMS, Brow + (size_t)(t + 2) * 64, ldB);
    }
    cur ^= 1;
  }
}

// ---- 256x256-tile mainloop (512 thr, 8 waves = 2M x 4N) ----
// Per wave: 128x64 output (8x4 frags), 64 MFMA per K-tile vs 8 staged
// loads/thread — 2x the MFMA:byte ratio of the 128 tile.
__device__ __forceinline__ void gemm_mainloop256(
    const __bf16* __restrict__ Arow, size_t ldA,
    const __bf16* __restrict__ Brow, size_t ldB,
    int K, __bf16* As, __bf16* Bs, f32x4 acc[8][4]) {
  int lane = threadIdx.x & 63, wave = threadIdx.x >> 6;
  int wm = (wave >> 2) * 128, wn = (wave & 3) * 64;
  int fr = lane & 15, fk = (lane >> 4) * 8;
  int nt = K >> 6;
  stage_tile256(As, Arow, ldA);
  stage_tile256(Bs, Brow, ldB);
  stage_tile256(As + TILE256_ELEMS, Arow + 64, ldA);
  stage_tile256(Bs + TILE256_ELEMS, Brow + 64, ldB);
  int cur = 0;
  for (int t = 0; t < nt; ++t) {
    if (t + 1 < nt) asm volatile("s_waitcnt vmcnt(8)" ::: "memory");
    else            asm volatile("s_waitcnt vmcnt(0)" ::: "memory");
    __builtin_amdgcn_s_barrier();
    __builtin_amdgcn_sched_barrier(0);
    const __bf16* Ab = As + cur * TILE256_ELEMS;
    const __bf16* Bb = Bs + cur * TILE256_ELEMS;
#pragma unroll
    for (int kk = 0; kk < 2; ++kk) {
      bf16x8 af[8], bfv[4];
#pragma unroll
      for (int mi = 0; mi < 8; ++mi) af[mi] = frag_ld(Ab, wm + mi * 16 + fr, kk * 32 + fk);
#pragma unroll
      for (int ni = 0; ni < 4; ++ni) bfv[ni] = frag_ld(Bb, wn + ni * 16 + fr, kk * 32 + fk);
      __builtin_amdgcn_s_setprio(1);
#pragma unroll
      for (int mi = 0; mi < 8; ++mi)
#pragma unroll
        for (int ni = 0; ni < 4; ++ni)
          acc[mi][ni] = __builtin_amdgcn_mfma_f32_16x16x32_bf16(af[mi], bfv[ni], acc[mi][ni], 0, 0, 0);
      __builtin_amdgcn_s_setprio(0);
    }
    __builtin_amdgcn_sched_barrier(0);
    __builtin_amdgcn_s_barrier();
    if (t + 2 < nt) {
      stage_tile256(As + cur * TILE256_ELEMS, Arow + (size_t)(t + 2) * 64, ldA);
      stage_tile256(Bs + cur * TILE256_ELEMS, Brow + (size_t)(t + 2) * 64, ldB);
    }
    cur ^= 1;
  }
}

// XCD-chunked swizzles
__device__ __forceinline__ unsigned xcd_swz_3072(unsigned bid) {
  return (bid & 7u) * 384u + (bid >> 3);
}
__device__ __forceinline__ unsigned xcd_swz_768(unsigned bid) {
  return (bid & 7u) * 96u + (bid >> 3);
}

// ---- K2: VT[e][m] = sum_d WvT[e][d] * msa[m][d]  (= V^T), 256^2 tile ----
// grid (2, 384): x = e-tile, y = msa panel
__global__ __launch_bounds__(512, 1) void gemm_vt_kernel(
    const __bf16* __restrict__ WvT, const __bf16* __restrict__ msa,
    __bf16* __restrict__ VT) {
  __shared__ __bf16 As[2 * TILE256_ELEMS], Bs[2 * TILE256_ELEMS];
  unsigned swz = xcd_swz_768(blockIdx.x + 2 * blockIdx.y);
  int m0 = (swz & 1) * 256;        // e-tile (WvT rows)
  int n0 = (swz >> 1) * 256;       // msa panel
  f32x4 acc[8][4] = {};
  gemm_mainloop256(WvT + (size_t)m0 * D_, D_, msa + (size_t)n0 * D_, D_, D_, As, Bs, acc);
  int lane = threadIdx.x & 63, wave = threadIdx.x >> 6;
  int wm = (wave >> 2) * 128, wn = (wave & 3) * 64;
  int cr = (lane >> 4) * 4, cc = lane & 15;
#pragma unroll
  for (int mi = 0; mi < 8; ++mi)
#pragma unroll
    for (int ni = 0; ni < 4; ++ni)
#pragma unroll
      for (int rr = 0; rr < 4; ++rr) {
        int row = m0 + wm + mi * 16 + cr + rr;
        int col = n0 + wn + ni * 16 + cc;
        VT[(size_t)row * M1_ + col] = f2bf(acc[mi][ni][rr]);
      }
}

// ---- K5: out2[(r,i)][h*128+d] = sum_j attn[h][i][j] * VT[h*128+d][r*384+j] ----
__global__ __launch_bounds__(256) void attnv_kernel(
    const __bf16* __restrict__ attn, const __bf16* __restrict__ VT,
    __bf16* __restrict__ out2) {
  __shared__ __bf16 As[2 * TILE_ELEMS], Bs[2 * TILE_ELEMS];
  unsigned swz = xcd_swz_3072(blockIdx.x + 3 * blockIdx.y);
  int it = swz % 3u;               // i-tile (share-group of 3; 384 % 3 == 0)
  int rh = swz / 3u;               // 0..1023
  int h = rh & 3, r = rh >> 2;
  const __bf16* A = attn + (size_t)h * LL2_ + (size_t)it * 128 * L_;
  const __bf16* Bt = VT + (size_t)(h * 128) * M1_ + (size_t)r * L_;
  f32x4 acc[4][4] = {};
  gemm_mainloop(A, L_, Bt, M1_, L_, As, Bs, acc);
  int lane = threadIdx.x & 63, wave = threadIdx.x >> 6;
  int wm = (wave >> 1) * 64, wn = (wave & 1) * 64;
  int cr = (lane >> 4) * 4, cc = lane & 15;
#pragma unroll
  for (int mi = 0; mi < 4; ++mi)
#pragma unroll
    for (int ni = 0; ni < 4; ++ni)
#pragma unroll
      for (int rr = 0; rr < 4; ++rr) {
        int row_i = it * 128 + wm + mi * 16 + cr + rr;
        int col = h * 128 + wn + ni * 16 + cc;
        out2[((size_t)r * L_ + row_i) * D_ + col] = f2bf(acc[mi][ni][rr]);
      }
}

// ---- K6: out[m][f] = x[m][f] + sum_e out2[m][e] * WoT[f][e], 256^2 tile ----
// grid (2, 384): x = f-tile (WoT rows), y = out2 panel
__global__ __launch_bounds__(512, 1) void gemm_out_kernel(
    const __bf16* __restrict__ out2, const __bf16* __restrict__ WoT,
    const float* __restrict__ x, float* __restrict__ out) {
  __shared__ __bf16 As[2 * TILE256_ELEMS], Bs[2 * TILE256_ELEMS];
  unsigned swz = xcd_swz_768(blockIdx.x + 2 * blockIdx.y);
  int n0 = (swz & 1) * 256;        // f-tile
  int m0 = (swz >> 1) * 256;       // out2 panel
  f32x4 acc[8][4] = {};
  gemm_mainloop256(out2 + (size_t)m0 * D_, D_, WoT + (size_t)n0 * D_, D_, D_, As, Bs, acc);
  int lane = threadIdx.x & 63, wave = threadIdx.x >> 6;
  int wm = (wave >> 2) * 128, wn = (wave & 3) * 64;
  int cr = (lane >> 4) * 4, cc = lane & 15;
#pragma unroll
  for (int mi = 0; mi < 8; ++mi)
#pragma unroll
    for (int ni = 0; ni < 4; ++ni)
#pragma unroll
      for (int rr = 0; rr < 4; ++rr) {
        int row = m0 + wm + mi * 16 + cr + rr;
        int col = n0 + wn + ni * 16 + cc;
        size_t idx = (size_t)row * D_ + col;
        out[idx] = x[idx] + acc[mi][ni][rr];
      }
}

extern "C" void kernel_launch(void* const* d_in, const int* in_sizes, int n_in,
                              void* d_out, int out_size, void* d_ws, size_t ws_size,
                              hipStream_t stream) {
  const float* x      = (const float*)d_in[0];
  const float* pair   = (const float*)d_in[1];
  const int*   mask   = (const int*)d_in[2];
  const float* g_msa  = (const float*)d_in[3];
  const float* b_msa  = (const float*)d_in[4];
  const float* g_pair = (const float*)d_in[5];
  const float* b_pair = (const float*)d_in[6];
  const float* Wp     = (const float*)d_in[7];
  const float* Wv     = (const float*)d_in[8];
  const float* Wo     = (const float*)d_in[9];
  float* out = (float*)d_out;

  char* p = (char*)d_ws;
  auto alloc = [&](size_t bytes) {
    char* r = p;
    p += (bytes + 255) & ~(size_t)255;
    return r;
  };
  __bf16* msa    = (__bf16*)alloc((size_t)M1_ * D_ * 2);  // 100.7 MB (aliased as out2 later)
  __bf16* VT     = (__bf16*)alloc((size_t)D_ * M1_ * 2);  // 100.7 MB
  float*  logits = (float*)alloc((size_t)H_ * LL2_ * 4);  // 2.36 MB
  __bf16* attn   = (__bf16*)alloc((size_t)H_ * LL2_ * 2); // 1.18 MB
  __bf16* WvT    = (__bf16*)alloc((size_t)512 * 512 * 2);
  __bf16* WoT    = (__bf16*)alloc((size_t)512 * 512 * 2);
  __bf16* out2   = msa;  // msa dead after gemm_vt_kernel

  wtrans_kernel<<<2048, 256, 0, stream>>>(Wv, Wo, WvT, WoT);
  ln_msa_kernel<<<M1_ / 4, 256, 0, stream>>>(x, g_msa, b_msa, msa);
  gemm_vt_kernel<<<dim3(2, M1_ / 256), 512, 0, stream>>>(WvT, msa, VT);
  pair_logits_kernel<<<NPAIR_BLOCKS, 256, 0, stream>>>(pair, mask, g_pair, b_pair, Wp, logits);
  softmax_kernel<<<(H_ * L_) / 4, 256, 0, stream>>>(logits, attn);
  attnv_kernel<<<dim3(3, RR_ * H_), 256, 0, stream>>>(attn, VT, out2);
  gemm_out_kernel<<<dim3(2, M1_ / 256), 512, 0, stream>>>(out2, WoT, x, out);
}